// Round 2
// baseline (1029.784 us; speedup 1.0000x reference)
//
#include <hip/hip_runtime.h>
#include <hip/hip_bf16.h>

// ---------------------------------------------------------------------------
// MyAttention: B=512, N=1, Np=255, C=768, H=12, hd=64, L=256, scale=0.125
//
// Reassociated (no K/V materialization):
//   q  = scale*(x @ wq + bq)                       K1 (split-K GEMM) + R1
//   qk[b,h,c]  = sum_d wk[c,h*64+d] q[b,h*64+d]    K2 (GEMM-T, z=head)
//   qbk[b,h]   = bk_h . q_bh                       K2b
//   logit[b,h,l] = xp[b,l,:].qk[b,h,:] + qbk       K3 fused (raw_attn out)
//   s[b,h,:]   = (scale/sum e) * sum_l e_l xp_l    K3 fused
//   ctx        = s . wv + scale*bv                 K6 (split-K GEMM) + R6
//   x_cls      = ctx @ wp + bp + x                 K7 (split-K GEMM) + R7
// ---------------------------------------------------------------------------

#define SCALE 0.125f

// ---------------------------------------------------------------------------
// fp32 tiled GEMM, 64x64 tile, 256 threads, 4x4/thread, K-step 16.
// blockIdx.z = zH * kParts + zK:  zH selects per-head panel (aZ/bZ/cZ flat
// offsets), zK selects a K-chunk of length K/kParts starting at zK*(K/kParts).
// Output goes to C + zH*cZ + zK*pStride (raw partial when kParts>1).
// BT=true: B element = B[n*ldb + zH*bZ + k] (B given transposed; kParts==1).
// ---------------------------------------------------------------------------
template<bool BT>
__global__ __launch_bounds__(256) void gemm_k(
    const float* __restrict__ A, int lda, int aZ,
    const float* __restrict__ B, int ldb, int bZ,
    const float* __restrict__ bias, int biasZ, float bscale,
    const float* __restrict__ res,
    float* __restrict__ C, int ldc, int cZ, long pStride,
    int K, int kParts, float mul)
{
    __shared__ float As[16][68];
    __shared__ float Bs[16][68];
    const int tid = threadIdx.x;
    const int n0 = blockIdx.x * 64;
    const int m0 = blockIdx.y * 64;
    const int z  = blockIdx.z;
    const int zH = z / kParts;
    const int zK = z % kParts;
    const int kLen = K / kParts;
    const int kOff = zK * kLen;
    const float* Ab = A + (size_t)zH * aZ;

    float acc[4][4];
#pragma unroll
    for (int i = 0; i < 4; ++i)
#pragma unroll
        for (int j = 0; j < 4; ++j) acc[i][j] = 0.f;

    const int tx = tid & 15;   // n-group
    const int ty = tid >> 4;   // m-group

    for (int k0 = 0; k0 < kLen; k0 += 16) {
        __syncthreads();
        {   // stage A tile [64 m x 16 k] transposed into As[k][m]
            const int i = tid >> 2, kq = tid & 3;
            float4 v = *(const float4*)&Ab[(size_t)(m0 + i) * lda + kOff + k0 + 4*kq];
            As[4*kq+0][i] = v.x; As[4*kq+1][i] = v.y;
            As[4*kq+2][i] = v.z; As[4*kq+3][i] = v.w;
        }
        if (!BT) {  // stage B tile [16 k x 64 n]
            const int kk = tid >> 4, n4 = tid & 15;
            float4 v = *(const float4*)&B[(size_t)(kOff + k0 + kk) * ldb + (size_t)zH*bZ + n0 + 4*n4];
            *(float4*)&Bs[kk][4*n4] = v;
        } else {    // B transposed source: rows are n, cols are k
            const int nn = tid >> 2, kq = tid & 3;
            float4 v = *(const float4*)&B[(size_t)(n0 + nn) * ldb + (size_t)zH*bZ + kOff + k0 + 4*kq];
            Bs[4*kq+0][nn] = v.x; Bs[4*kq+1][nn] = v.y;
            Bs[4*kq+2][nn] = v.z; Bs[4*kq+3][nn] = v.w;
        }
        __syncthreads();
#pragma unroll
        for (int kk = 0; kk < 16; ++kk) {
            float4 a4 = *(const float4*)&As[kk][4*ty];
            float4 b4 = *(const float4*)&Bs[kk][4*tx];
            float av[4] = {a4.x, a4.y, a4.z, a4.w};
            float bv[4] = {b4.x, b4.y, b4.z, b4.w};
#pragma unroll
            for (int i = 0; i < 4; ++i)
#pragma unroll
                for (int j = 0; j < 4; ++j) acc[i][j] += av[i] * bv[j];
        }
    }

    float* Cb = C + (size_t)zH * cZ + (size_t)zK * pStride;
    float bv4[4] = {0.f, 0.f, 0.f, 0.f};
    if (bias) {
        float4 bb = *(const float4*)&bias[(size_t)zH*biasZ + n0 + 4*tx];
        bv4[0] = bscale*bb.x; bv4[1] = bscale*bb.y; bv4[2] = bscale*bb.z; bv4[3] = bscale*bb.w;
    }
#pragma unroll
    for (int i = 0; i < 4; ++i) {
        const int m = m0 + 4*ty + i;
        float v[4];
#pragma unroll
        for (int j = 0; j < 4; ++j) v[j] = mul * acc[i][j] + bv4[j];
        if (res) {
            float4 rv = *(const float4*)&res[(size_t)m * 768 + n0 + 4*tx];
            v[0] += rv.x; v[1] += rv.y; v[2] += rv.z; v[3] += rv.w;
        }
        float4 out = {v[0], v[1], v[2], v[3]};
        *(float4*)&Cb[(size_t)m * ldc + n0 + 4*tx] = out;
    }
}

// ---------------------------------------------------------------------------
// Split-K reduction over full [512x768] partial matrices:
//   out = mul * sum_s part[s] + bscale*bias[col] (+ res)
// ---------------------------------------------------------------------------
__global__ __launch_bounds__(256) void reduce_k(
    const float* __restrict__ part, long pStride, int S,
    const float* __restrict__ bias, float bscale,
    const float* __restrict__ res,
    float* __restrict__ out, float mul)
{
    const int f4 = blockIdx.x * 256 + threadIdx.x;   // 98304 float4s
    const int idx = f4 * 4;
    const int n = idx % 768;
    float4 a = *(const float4*)&part[idx];
#pragma unroll 4
    for (int s = 1; s < S; ++s) {
        float4 p = *(const float4*)&part[(size_t)s * pStride + idx];
        a.x += p.x; a.y += p.y; a.z += p.z; a.w += p.w;
    }
    float4 bb = *(const float4*)&bias[n];
    float4 v = {mul*a.x + bscale*bb.x, mul*a.y + bscale*bb.y,
                mul*a.z + bscale*bb.z, mul*a.w + bscale*bb.w};
    if (res) {
        float4 rv = *(const float4*)&res[idx];
        v.x += rv.x; v.y += rv.y; v.z += rv.z; v.w += rv.w;
    }
    *(float4*)&out[idx] = v;
}

// ---------------------------------------------------------------------------
// K2b: qbk[b,h] = sum_d bk[h*64+d] * q[b,h*64+d].  One wave per (b,h).
// ---------------------------------------------------------------------------
__global__ __launch_bounds__(256) void qbk_k(
    const float* __restrict__ q, const float* __restrict__ bk,
    float* __restrict__ qbk)
{
    const int task = blockIdx.x * 4 + (threadIdx.x >> 6);  // 6144 tasks
    const int ln = threadIdx.x & 63;
    const int b = task / 12, h = task % 12;
    float v = q[(size_t)b * 768 + h * 64 + ln] * bk[h * 64 + ln];
#pragma unroll
    for (int off = 32; off > 0; off >>= 1) v += __shfl_xor(v, off);
    if (ln == 0) qbk[task] = v;
}

// ---------------------------------------------------------------------------
// K3: fused logits + softmax + attention-weighted xp sum.  Block = one batch.
// 4 waves; wave w owns heads 3w..3w+2.  Lane owns 12 cols (3x float4 at
// dword cols {4*ln, 256+4*ln, 512+4*ln}).  qk + accumulators in registers.
//
// Reduction: rows processed in groups of 4.  Each lane's 12 partials
// (3 heads x 4 rows) go to LDS once; lanes 0..47 each reduce one (head,row)
// pair over 16-lane segments (4x b128 + 2 shfl_xor), add qbk, write the raw
// logit to p_lds and exp() to a 12-float broadcast buffer all lanes re-read.
// Replaces the per-(row,head) 6-step 64-wide butterfly (~5x fewer LDS ops).
// ---------------------------------------------------------------------------
__global__ __launch_bounds__(256, 2) void attn_fused_k(
    const float* __restrict__ x, const float* __restrict__ prompts,
    const float* __restrict__ qk_in, const float* __restrict__ qbk,
    float* __restrict__ s_out, float* __restrict__ raw_attn)
{
    __shared__ float xs[16 * 772];       // 16 rows, padded stride 772
    __shared__ float p_lds[12 * 256];    // raw logits for the whole batch
    __shared__ float red[4][12][68];     // per-wave partial-transpose buffer
    __shared__ float ebuf[4][16];        // per-wave e broadcast (12 used)
    const int b = blockIdx.x;
    const int tid = threadIdx.x;
    const int wid = tid >> 6, ln = tid & 63;
    const int pair = ln >> 2, seg = ln & 3;   // reduce-role decode

    // qk + bias-dot into registers
    float qkr[3][12];
    float qb[3];
#pragma unroll
    for (int h3 = 0; h3 < 3; ++h3) {
        const int h = 3 * wid + h3;
        const float* base = qk_in + ((size_t)(b * 12 + h)) * 768 + 4 * ln;
#pragma unroll
        for (int qc = 0; qc < 3; ++qc) {
            float4 v = *(const float4*)(base + qc * 256);
            qkr[h3][qc*4+0] = v.x; qkr[h3][qc*4+1] = v.y;
            qkr[h3][qc*4+2] = v.z; qkr[h3][qc*4+3] = v.w;
        }
        qb[h3] = qbk[b * 12 + h];
    }
    // qb selected by runtime pair>>2 later; precompute via cndmask chain
    const float qb_sel = (pair >= 8) ? qb[2] : ((pair >= 4) ? qb[1] : qb[0]);

    float acc[3][12];
#pragma unroll
    for (int h3 = 0; h3 < 3; ++h3)
#pragma unroll
        for (int j = 0; j < 12; ++j) acc[h3][j] = 0.f;
    float dsum[3] = {0.f, 0.f, 0.f};

    for (int t = 0; t < 16; ++t) {
        __syncthreads();   // protect xs from previous iteration's readers
        // cooperative stage of 16 xp rows (row 0 of xp == x[b], rest prompts)
#pragma unroll
        for (int i = 0; i < 12; ++i) {
            const int f = tid + 256 * i;       // 0..3071 float4s
            const int row = f / 192, c4 = f % 192;
            const int l = t * 16 + row;
            const float* src = (l == 0)
                ? (x + (size_t)b * 768 + 4 * c4)
                : (prompts + ((size_t)b * 255 + (l - 1)) * 768 + 4 * c4);
            float4 v = *(const float4*)src;
            *(float4*)&xs[row * 772 + 4 * c4] = v;
        }
        __syncthreads();

        for (int g = 0; g < 4; ++g) {          // groups of 4 rows
            const int l0 = t * 16 + 4 * g;
            // load 4 rows x 12 cols, compute 12 partial dots
            float xvb[4][12];
            float pp[3][4];
#pragma unroll
            for (int r = 0; r < 4; ++r) {
#pragma unroll
                for (int qc = 0; qc < 3; ++qc) {
                    float4 v = *(const float4*)&xs[(4*g + r) * 772 + qc * 256 + 4 * ln];
                    xvb[r][qc*4+0] = v.x; xvb[r][qc*4+1] = v.y;
                    xvb[r][qc*4+2] = v.z; xvb[r][qc*4+3] = v.w;
                }
#pragma unroll
                for (int h3 = 0; h3 < 3; ++h3) {
                    float p = 0.f;
#pragma unroll
                    for (int j = 0; j < 12; ++j) p += xvb[r][j] * qkr[h3][j];
                    pp[h3][r] = p;
                }
            }
            // scatter partials: red[wid][h3*4+r][ln]
#pragma unroll
            for (int h3 = 0; h3 < 3; ++h3)
#pragma unroll
                for (int r = 0; r < 4; ++r)
                    red[wid][h3*4 + r][ln] = pp[h3][r];

            // lanes 0..47: pair = h3*4+r, seg sums 16 partials
            float tot = 0.f;
            if (pair < 12) {
                const float* rp = &red[wid][pair][16 * seg];
                float4 s0 = *(const float4*)(rp + 0);
                float4 s1 = *(const float4*)(rp + 4);
                float4 s2 = *(const float4*)(rp + 8);
                float4 s3 = *(const float4*)(rp + 12);
                tot = ((s0.x+s0.y)+(s0.z+s0.w)) + ((s1.x+s1.y)+(s1.z+s1.w))
                    + ((s2.x+s2.y)+(s2.z+s2.w)) + ((s3.x+s3.y)+(s3.z+s3.w));
            }
            tot += __shfl_xor(tot, 1);
            tot += __shfl_xor(tot, 2);
            tot += qb_sel;
            if (pair < 12) {
                if (seg == 0) {
                    p_lds[(3*wid + (pair >> 2)) * 256 + l0 + (pair & 3)] = tot;
                    ebuf[wid][pair] = exp2f(tot * 1.44269504088896f);
                }
            }
            // broadcast e back to all lanes
            float ev[12];
            {
                float4 e0 = *(const float4*)&ebuf[wid][0];
                float4 e1 = *(const float4*)&ebuf[wid][4];
                float4 e2 = *(const float4*)&ebuf[wid][8];
                ev[0]=e0.x; ev[1]=e0.y; ev[2]=e0.z; ev[3]=e0.w;
                ev[4]=e1.x; ev[5]=e1.y; ev[6]=e1.z; ev[7]=e1.w;
                ev[8]=e2.x; ev[9]=e2.y; ev[10]=e2.z; ev[11]=e2.w;
            }
#pragma unroll
            for (int h3 = 0; h3 < 3; ++h3) {
#pragma unroll
                for (int r = 0; r < 4; ++r) {
                    const float e = ev[h3*4 + r];
                    dsum[h3] += e;
#pragma unroll
                    for (int j = 0; j < 12; ++j) acc[h3][j] += e * xvb[r][j];
                }
            }
        }
    }

    // finalize s = (scale / dsum) * acc   (overwrites this wave's own qk rows)
#pragma unroll
    for (int h3 = 0; h3 < 3; ++h3) {
        const float inv = SCALE / dsum[h3];
        const int h = 3 * wid + h3;
        float* base = s_out + ((size_t)(b * 12 + h)) * 768 + 4 * ln;
#pragma unroll
        for (int qc = 0; qc < 3; ++qc) {
            float4 v = {acc[h3][qc*4+0] * inv, acc[h3][qc*4+1] * inv,
                        acc[h3][qc*4+2] * inv, acc[h3][qc*4+3] * inv};
            *(float4*)(base + qc * 256) = v;
        }
    }

    __syncthreads();
    // write raw_attn [b][h][l], coalesced
#pragma unroll
    for (int i = 0; i < 12; ++i)
        raw_attn[(size_t)b * 3072 + i * 256 + tid] = p_lds[i * 256 + tid];
}

// ---------------------------------------------------------------------------
extern "C" void kernel_launch(void* const* d_in, const int* in_sizes, int n_in,
                              void* d_out, int out_size, void* d_ws, size_t ws_size,
                              hipStream_t stream) {
    const float* x       = (const float*)d_in[0];  // [512,1,768]
    const float* prompts = (const float*)d_in[1];  // [512,255,768]
    const float* wq      = (const float*)d_in[2];
    const float* bq      = (const float*)d_in[3];
    const float* wk      = (const float*)d_in[4];
    const float* bk      = (const float*)d_in[5];
    const float* wv      = (const float*)d_in[6];
    const float* bv      = (const float*)d_in[7];
    const float* wp      = (const float*)d_in[8];
    const float* bp      = (const float*)d_in[9];

    float* out_x    = (float*)d_out;            // x_cls: 512*768
    float* out_attn = out_x + 512 * 768;        // raw_attn: 512*12*256

    // workspace layout (ctx aliases q; s aliases qk — lifetimes disjoint)
    float* q_ws   = (float*)d_ws;               // 393216
    float* qk_ws  = q_ws + 393216;              // 512*12*768 (also s_ws)
    float* qbk_ws = qk_ws + 4718592;            // 6144
    float* part   = qbk_ws + 8192;              // 4 * 393216 split-K partials
    float* ctx_ws = q_ws;                       // q dead after K2/K2b

    const long PS = 393216;

    // K1: q = scale*(x @ wq + bq), split-K=4
    hipLaunchKernelGGL((gemm_k<false>), dim3(12, 8, 4), dim3(256), 0, stream,
        x, 768, 0,  wq, 768, 0,  nullptr, 0, 0.f,  nullptr,
        part, 768, 0, PS,  768, 4, 1.0f);
    hipLaunchKernelGGL(reduce_k, dim3(384), dim3(256), 0, stream,
        part, PS, 4, bq, SCALE, nullptr, q_ws, SCALE);

    // K2b: qbk[b,h] = bk_h . q_bh
    hipLaunchKernelGGL(qbk_k, dim3(1536), dim3(256), 0, stream,
        q_ws, bk, qbk_ws);

    // K2: qk[b,h,c] = sum_d q[b,h*64+d]*wk[c,h*64+d]   (z=head, K=64, B^T)
    hipLaunchKernelGGL((gemm_k<true>), dim3(12, 8, 12), dim3(256), 0, stream,
        q_ws, 768, 64,  wk, 768, 64,  nullptr, 0, 0.f,  nullptr,
        qk_ws, 9216, 768, 0,  64, 1, 1.0f);

    // K3: fused logits -> raw_attn, softmax, s = sum_l attn*xp (s aliases qk)
    hipLaunchKernelGGL(attn_fused_k, dim3(512), dim3(256), 0, stream,
        x, prompts, qk_ws, qbk_ws, qk_ws, out_attn);

    // K6: ctx[b,h*64+d] = s[b,h,:].wv[:,h*64+d] + scale*bv, split-K=4, z=head
    hipLaunchKernelGGL((gemm_k<false>), dim3(1, 8, 48), dim3(256), 0, stream,
        qk_ws, 9216, 768,  wv, 768, 64,  nullptr, 0, 0.f,  nullptr,
        part, 768, 64, PS,  768, 4, 1.0f);
    hipLaunchKernelGGL(reduce_k, dim3(384), dim3(256), 0, stream,
        part, PS, 4, bv, SCALE, nullptr, ctx_ws, 1.0f);

    // K7: x_cls = ctx @ wp + bp + x, split-K=4
    hipLaunchKernelGGL((gemm_k<false>), dim3(12, 8, 4), dim3(256), 0, stream,
        ctx_ws, 768, 0,  wp, 768, 0,  nullptr, 0, 0.f,  nullptr,
        part, 768, 0, PS,  768, 4, 1.0f);
    hipLaunchKernelGGL(reduce_k, dim3(384), dim3(256), 0, stream,
        part, PS, 4, bp, 1.0f, x, out_x, 1.0f);
}

// Round 5
// 659.906 us; speedup vs baseline: 1.5605x; 1.5605x over previous
//
#include <hip/hip_runtime.h>
#include <hip/hip_bf16.h>

// ---------------------------------------------------------------------------
// MyAttention: B=512, N=1, Np=255, C=768, H=12, hd=64, L=256, scale=0.125
//
// Reassociated (no K/V materialization):
//   q  = scale*(x @ wq + bq)                       K1 (split-K GEMM) + R1
//   qk[b,h,c]  = sum_d wk[c,h*64+d] q[b,h*64+d]    K2 (GEMM-T, z=head)
//   qbk[b,h]   = bk_h . q_bh                       K2b
//   logit[b,h,l] = xp[b,l,:].qk[b,h,:] + qbk       K3 fused (raw_attn out)
//   s[b,h,:]   = (scale/sum e) * sum_l e_l xp_l    K3 fused
//   ctx        = s . wv + scale*bv                 K6 (split-K GEMM) + R6
//   x_cls      = ctx @ wp + bp + x                 K7 (split-K GEMM) + R7
// ---------------------------------------------------------------------------

#define SCALE 0.125f

// ---------------------------------------------------------------------------
// fp32 tiled GEMM, 64x64 tile, 256 threads, 4x4/thread, K-step 16.
// blockIdx.z = zH * kParts + zK.  See round-1 notes.
// ---------------------------------------------------------------------------
template<bool BT>
__global__ __launch_bounds__(256) void gemm_k(
    const float* __restrict__ A, int lda, int aZ,
    const float* __restrict__ B, int ldb, int bZ,
    const float* __restrict__ bias, int biasZ, float bscale,
    const float* __restrict__ res,
    float* __restrict__ C, int ldc, int cZ, long pStride,
    int K, int kParts, float mul)
{
    __shared__ float As[16][68];
    __shared__ float Bs[16][68];
    const int tid = threadIdx.x;
    const int n0 = blockIdx.x * 64;
    const int m0 = blockIdx.y * 64;
    const int z  = blockIdx.z;
    const int zH = z / kParts;
    const int zK = z % kParts;
    const int kLen = K / kParts;
    const int kOff = zK * kLen;
    const float* Ab = A + (size_t)zH * aZ;

    float acc[4][4];
#pragma unroll
    for (int i = 0; i < 4; ++i)
#pragma unroll
        for (int j = 0; j < 4; ++j) acc[i][j] = 0.f;

    const int tx = tid & 15;   // n-group
    const int ty = tid >> 4;   // m-group

    for (int k0 = 0; k0 < kLen; k0 += 16) {
        __syncthreads();
        {   // stage A tile [64 m x 16 k] transposed into As[k][m]
            const int i = tid >> 2, kq = tid & 3;
            float4 v = *(const float4*)&Ab[(size_t)(m0 + i) * lda + kOff + k0 + 4*kq];
            As[4*kq+0][i] = v.x; As[4*kq+1][i] = v.y;
            As[4*kq+2][i] = v.z; As[4*kq+3][i] = v.w;
        }
        if (!BT) {  // stage B tile [16 k x 64 n]
            const int kk = tid >> 4, n4 = tid & 15;
            float4 v = *(const float4*)&B[(size_t)(kOff + k0 + kk) * ldb + (size_t)zH*bZ + n0 + 4*n4];
            *(float4*)&Bs[kk][4*n4] = v;
        } else {    // B transposed source: rows are n, cols are k
            const int nn = tid >> 2, kq = tid & 3;
            float4 v = *(const float4*)&B[(size_t)(n0 + nn) * ldb + (size_t)zH*bZ + kOff + k0 + 4*kq];
            Bs[4*kq+0][nn] = v.x; Bs[4*kq+1][nn] = v.y;
            Bs[4*kq+2][nn] = v.z; Bs[4*kq+3][nn] = v.w;
        }
        __syncthreads();
#pragma unroll
        for (int kk = 0; kk < 16; ++kk) {
            float4 a4 = *(const float4*)&As[kk][4*ty];
            float4 b4 = *(const float4*)&Bs[kk][4*tx];
            float av[4] = {a4.x, a4.y, a4.z, a4.w};
            float bv[4] = {b4.x, b4.y, b4.z, b4.w};
#pragma unroll
            for (int i = 0; i < 4; ++i)
#pragma unroll
                for (int j = 0; j < 4; ++j) acc[i][j] += av[i] * bv[j];
        }
    }

    float* Cb = C + (size_t)zH * cZ + (size_t)zK * pStride;
    float bv4[4] = {0.f, 0.f, 0.f, 0.f};
    if (bias) {
        float4 bb = *(const float4*)&bias[(size_t)zH*biasZ + n0 + 4*tx];
        bv4[0] = bscale*bb.x; bv4[1] = bscale*bb.y; bv4[2] = bscale*bb.z; bv4[3] = bscale*bb.w;
    }
#pragma unroll
    for (int i = 0; i < 4; ++i) {
        const int m = m0 + 4*ty + i;
        float v[4];
#pragma unroll
        for (int j = 0; j < 4; ++j) v[j] = mul * acc[i][j] + bv4[j];
        if (res) {
            float4 rv = *(const float4*)&res[(size_t)m * 768 + n0 + 4*tx];
            v[0] += rv.x; v[1] += rv.y; v[2] += rv.z; v[3] += rv.w;
        }
        float4 out = {v[0], v[1], v[2], v[3]};
        *(float4*)&Cb[(size_t)m * ldc + n0 + 4*tx] = out;
    }
}

// ---------------------------------------------------------------------------
// Split-K reduction over full [512x768] partial matrices.
// ---------------------------------------------------------------------------
__global__ __launch_bounds__(256) void reduce_k(
    const float* __restrict__ part, long pStride, int S,
    const float* __restrict__ bias, float bscale,
    const float* __restrict__ res,
    float* __restrict__ out, float mul)
{
    const int f4 = blockIdx.x * 256 + threadIdx.x;
    const int idx = f4 * 4;
    const int n = idx % 768;
    float4 a = *(const float4*)&part[idx];
#pragma unroll 4
    for (int s = 1; s < S; ++s) {
        float4 p = *(const float4*)&part[(size_t)s * pStride + idx];
        a.x += p.x; a.y += p.y; a.z += p.z; a.w += p.w;
    }
    float4 bb = *(const float4*)&bias[n];
    float4 v = {mul*a.x + bscale*bb.x, mul*a.y + bscale*bb.y,
                mul*a.z + bscale*bb.z, mul*a.w + bscale*bb.w};
    if (res) {
        float4 rv = *(const float4*)&res[idx];
        v.x += rv.x; v.y += rv.y; v.z += rv.z; v.w += rv.w;
    }
    *(float4*)&out[idx] = v;
}

// ---------------------------------------------------------------------------
// K2b: qbk[b,h] = sum_d bk[h*64+d] * q[b,h*64+d].  One wave per (b,h).
// ---------------------------------------------------------------------------
__global__ __launch_bounds__(256) void qbk_k(
    const float* __restrict__ q, const float* __restrict__ bk,
    float* __restrict__ qbk)
{
    const int task = blockIdx.x * 4 + (threadIdx.x >> 6);
    const int ln = threadIdx.x & 63;
    const int b = task / 12, h = task % 12;
    float v = q[(size_t)b * 768 + h * 64 + ln] * bk[h * 64 + ln];
#pragma unroll
    for (int off = 32; off > 0; off >>= 1) v += __shfl_xor(v, off);
    if (ln == 0) qbk[task] = v;
}

// ---------------------------------------------------------------------------
// Wave-wide sum with 4 DPP steps (VALU pipe) + 1 ds_swizzle + 1 shfl.
// Replaces the 6-step ds_permute butterfly: 6 LDS-pipe ops -> 2.
// ---------------------------------------------------------------------------
template<int CTRL>
__device__ __forceinline__ float dpp_add(float x) {
    int y = __builtin_amdgcn_update_dpp(0, __float_as_int(x), CTRL, 0xF, 0xF, true);
    return x + __int_as_float(y);
}

__device__ __forceinline__ float wave_reduce_sum(float p) {
    p = dpp_add<0xB1>(p);    // quad_perm [1,0,3,2]  : + lane^1
    p = dpp_add<0x4E>(p);    // quad_perm [2,3,0,1]  : + lane^2
    p = dpp_add<0x124>(p);   // row_ror:4  (quad sums -> 16-lane sum)
    p = dpp_add<0x128>(p);   // row_ror:8
    p += __int_as_float(__builtin_amdgcn_ds_swizzle(__float_as_int(p), 0x401F)); // xor 16
    p += __shfl_xor(p, 32);  // cross-half
    return p;
}

// ---------------------------------------------------------------------------
// K3: fused logits + softmax + attention-weighted xp sum.  Block = one batch.
// 4 waves; wave w owns heads 3w..3w+2.  Lane owns 12 cols (3x float4 at
// dword cols {4*ln, 256+4*ln, 512+4*ln}).  qk + accumulators in registers.
// Round-1 one-pass structure (xv transient -> no spills); reduction via DPP.
// All lanes hold the reduced logit, so exp/accumulate need no broadcast.
// ---------------------------------------------------------------------------
__global__ __launch_bounds__(256, 2) void attn_fused_k(
    const float* __restrict__ x, const float* __restrict__ prompts,
    const float* __restrict__ qk_in, const float* __restrict__ qbk,
    float* __restrict__ s_out, float* __restrict__ raw_attn)
{
    __shared__ float xs[16 * 772];     // 16 rows, padded stride 772
    __shared__ float p_lds[12 * 256];  // raw logits for the whole batch
    const int b = blockIdx.x;
    const int tid = threadIdx.x;
    const int wid = tid >> 6, ln = tid & 63;

    // qk + bias-dot into registers
    float qkr[3][12];
    float qb[3];
#pragma unroll
    for (int h3 = 0; h3 < 3; ++h3) {
        const int h = 3 * wid + h3;
        const float* base = qk_in + ((size_t)(b * 12 + h)) * 768 + 4 * ln;
#pragma unroll
        for (int qc = 0; qc < 3; ++qc) {
            float4 v = *(const float4*)(base + qc * 256);
            qkr[h3][qc*4+0] = v.x; qkr[h3][qc*4+1] = v.y;
            qkr[h3][qc*4+2] = v.z; qkr[h3][qc*4+3] = v.w;
        }
        qb[h3] = qbk[b * 12 + h];
    }

    float acc[3][12];
#pragma unroll
    for (int h3 = 0; h3 < 3; ++h3)
#pragma unroll
        for (int j = 0; j < 12; ++j) acc[h3][j] = 0.f;
    float dsum[3] = {0.f, 0.f, 0.f};

    for (int t = 0; t < 16; ++t) {
        __syncthreads();   // protect xs from previous iteration's readers
        // cooperative stage of 16 xp rows (row 0 of xp == x[b], rest prompts)
#pragma unroll
        for (int i = 0; i < 12; ++i) {
            const int f = tid + 256 * i;       // 0..3071 float4s
            const int row = f / 192, c4 = f % 192;
            const int l = t * 16 + row;
            const float* src = (l == 0)
                ? (x + (size_t)b * 768 + 4 * c4)
                : (prompts + ((size_t)b * 255 + (l - 1)) * 768 + 4 * c4);
            float4 v = *(const float4*)src;
            *(float4*)&xs[row * 772 + 4 * c4] = v;
        }
        __syncthreads();

        for (int r = 0; r < 16; ++r) {
            const int l = t * 16 + r;
            float xv[12];
#pragma unroll
            for (int qc = 0; qc < 3; ++qc) {
                float4 v = *(const float4*)&xs[r * 772 + qc * 256 + 4 * ln];
                xv[qc*4+0] = v.x; xv[qc*4+1] = v.y;
                xv[qc*4+2] = v.z; xv[qc*4+3] = v.w;
            }
            float lg[3];
#pragma unroll
            for (int h3 = 0; h3 < 3; ++h3) {
                float p = 0.f;
#pragma unroll
                for (int j = 0; j < 12; ++j) p += xv[j] * qkr[h3][j];
                lg[h3] = wave_reduce_sum(p) + qb[h3];
            }
            if (ln == 0) {
                p_lds[(3*wid + 0) * 256 + l] = lg[0];
                p_lds[(3*wid + 1) * 256 + l] = lg[1];
                p_lds[(3*wid + 2) * 256 + l] = lg[2];
            }
#pragma unroll
            for (int h3 = 0; h3 < 3; ++h3) {
                const float e = exp2f(lg[h3] * 1.44269504088896f);
                dsum[h3] += e;
#pragma unroll
                for (int j = 0; j < 12; ++j) acc[h3][j] += e * xv[j];
            }
        }
    }

    // finalize s = (scale / dsum) * acc   (overwrites this wave's own qk rows)
#pragma unroll
    for (int h3 = 0; h3 < 3; ++h3) {
        const float inv = SCALE / dsum[h3];
        const int h = 3 * wid + h3;
        float* base = s_out + ((size_t)(b * 12 + h)) * 768 + 4 * ln;
#pragma unroll
        for (int qc = 0; qc < 3; ++qc) {
            float4 v = {acc[h3][qc*4+0] * inv, acc[h3][qc*4+1] * inv,
                        acc[h3][qc*4+2] * inv, acc[h3][qc*4+3] * inv};
            *(float4*)(base + qc * 256) = v;
        }
    }

    __syncthreads();
    // write raw_attn [b][h][l], coalesced
#pragma unroll
    for (int i = 0; i < 12; ++i)
        raw_attn[(size_t)b * 3072 + i * 256 + tid] = p_lds[i * 256 + tid];
}

// ---------------------------------------------------------------------------
extern "C" void kernel_launch(void* const* d_in, const int* in_sizes, int n_in,
                              void* d_out, int out_size, void* d_ws, size_t ws_size,
                              hipStream_t stream) {
    const float* x       = (const float*)d_in[0];  // [512,1,768]
    const float* prompts = (const float*)d_in[1];  // [512,255,768]
    const float* wq      = (const float*)d_in[2];
    const float* bq      = (const float*)d_in[3];
    const float* wk      = (const float*)d_in[4];
    const float* bk      = (const float*)d_in[5];
    const float* wv      = (const float*)d_in[6];
    const float* bv      = (const float*)d_in[7];
    const float* wp      = (const float*)d_in[8];
    const float* bp      = (const float*)d_in[9];

    float* out_x    = (float*)d_out;            // x_cls: 512*768
    float* out_attn = out_x + 512 * 768;        // raw_attn: 512*12*256

    // workspace layout (ctx aliases q; s aliases qk — lifetimes disjoint)
    float* q_ws   = (float*)d_ws;               // 393216
    float* qk_ws  = q_ws + 393216;              // 512*12*768 (also s_ws)
    float* qbk_ws = qk_ws + 4718592;            // 6144
    float* part   = qbk_ws + 8192;              // 4 * 393216 split-K partials
    float* ctx_ws = q_ws;                       // q dead after K2/K2b

    const long PS = 393216;

    // K1: q = scale*(x @ wq + bq), split-K=4
    hipLaunchKernelGGL((gemm_k<false>), dim3(12, 8, 4), dim3(256), 0, stream,
        x, 768, 0,  wq, 768, 0,  nullptr, 0, 0.f,  nullptr,
        part, 768, 0, PS,  768, 4, 1.0f);
    hipLaunchKernelGGL(reduce_k, dim3(384), dim3(256), 0, stream,
        part, PS, 4, bq, SCALE, nullptr, q_ws, SCALE);

    // K2b: qbk[b,h] = bk_h . q_bh
    hipLaunchKernelGGL(qbk_k, dim3(1536), dim3(256), 0, stream,
        q_ws, bk, qbk_ws);

    // K2: qk[b,h,c] = sum_d q[b,h*64+d]*wk[c,h*64+d]   (z=head, K=64, B^T)
    hipLaunchKernelGGL((gemm_k<true>), dim3(12, 8, 12), dim3(256), 0, stream,
        q_ws, 768, 64,  wk, 768, 64,  nullptr, 0, 0.f,  nullptr,
        qk_ws, 9216, 768, 0,  64, 1, 1.0f);

    // K3: fused logits -> raw_attn, softmax, s = sum_l attn*xp (s aliases qk)
    hipLaunchKernelGGL(attn_fused_k, dim3(512), dim3(256), 0, stream,
        x, prompts, qk_ws, qbk_ws, qk_ws, out_attn);

    // K6: ctx[b,h*64+d] = s[b,h,:].wv[:,h*64+d] + scale*bv, split-K=4, z=head
    hipLaunchKernelGGL((gemm_k<false>), dim3(1, 8, 48), dim3(256), 0, stream,
        qk_ws, 9216, 768,  wv, 768, 64,  nullptr, 0, 0.f,  nullptr,
        part, 768, 64, PS,  768, 4, 1.0f);
    hipLaunchKernelGGL(reduce_k, dim3(384), dim3(256), 0, stream,
        part, PS, 4, bv, SCALE, nullptr, ctx_ws, 1.0f);

    // K7: x_cls = ctx @ wp + bp + x, split-K=4
    hipLaunchKernelGGL((gemm_k<false>), dim3(12, 8, 4), dim3(256), 0, stream,
        ctx_ws, 768, 0,  wp, 768, 0,  nullptr, 0, 0.f,  nullptr,
        part, 768, 0, PS,  768, 4, 1.0f);
    hipLaunchKernelGGL(reduce_k, dim3(384), dim3(256), 0, stream,
        part, PS, 4, bp, 1.0f, x, out_x, 1.0f);
}